// Round 1
// baseline (20106.117 us; speedup 1.0000x reference)
//
#include <hip/hip_runtime.h>
#include <hip/hip_cooperative_groups.h>

namespace cg = cooperative_groups;

#define Bn 32
#define Sn 64
#define Tn 64
#define Hn 512
#define Vn 32000

// ---- workspace layout (float offsets) ----
#define KP_OFF   0u            // keys_proj: 2048*512 = 1048576
#define H0_OFF   1048576u      // h buffer 0: 16384
#define H1_OFF   1064960u      // h buffer 1: 16384
#define CTX_OFF  1081344u      // context: 16384
#define PK_OFF   1097728u      // packed argmax: 64*32 ull = 4096 float slots (8B aligned)
#define TOK_OFF  1101824u      // tok: 32 int (legacy fallback only)
#define DONE_OFF 1101856u      // done counters: 64 uint (legacy fallback only)

// ---------------- keys_proj = einsum('bsh,gh->bsg', enc, Ua_w) + Ua_b ----------------
__global__ void __launch_bounds__(256) kp_kernel(const float* __restrict__ enc,
                                                 const float* __restrict__ Ua_w,
                                                 const float* __restrict__ Ua_b,
                                                 float* __restrict__ kp) {
  __shared__ __align__(16) float ea[32][68];
  __shared__ __align__(16) float ua[64][68];
  const int tid = threadIdx.x;
  const int bs0 = blockIdx.x * 32, g0 = blockIdx.y * 64;
  const int g_l = tid & 63;   // 0..63
  const int wv  = tid >> 6;   // 0..3
  float acc[8];
#pragma unroll
  for (int r = 0; r < 8; r++) acc[r] = 0.f;
  for (int kc = 0; kc < 8; kc++) {
    const int k0 = kc * 64;
#pragma unroll
    for (int r = 0; r < 8; r++) { int f = tid + r * 256; int b = f >> 6, k = f & 63;
      ea[b][k] = enc[(bs0 + b) * Hn + k0 + k]; }
#pragma unroll
    for (int r = 0; r < 16; r++) { int f = tid + r * 256; int g = f >> 6, k = f & 63;
      ua[g][k] = Ua_w[(g0 + g) * Hn + k0 + k]; }
    __syncthreads();
#pragma unroll
    for (int kk = 0; kk < 16; kk++) {
      float4 u4 = *(const float4*)&ua[g_l][kk * 4];
#pragma unroll
      for (int r = 0; r < 8; r++) {
        int bs_l = wv + 4 * r;
        float4 e4 = *(const float4*)&ea[bs_l][kk * 4];
        acc[r] += u4.x * e4.x + u4.y * e4.y + u4.z * e4.z + u4.w * e4.w;
      }
    }
    __syncthreads();
  }
  const float bias = Ua_b[g0 + g_l];
#pragma unroll
  for (int r = 0; r < 8; r++) {
    int bs = bs0 + wv + 4 * r;
    kp[bs * Hn + g0 + g_l] = acc[r] + bias;
  }
}

// =====================================================================================
// Persistent fused decode loop: one cooperative kernel runs all T=64 steps with
// grid.sync() between the attn -> gru -> logits phases (phase bodies identical to the
// previously-verified standalone kernels).
// =====================================================================================
struct DecArgs {
  const float* enc;
  const float* kp;
  const float* Wa_w;
  const float* Wa_b;
  const float* Va_w;
  const float* Va_b;
  const float* emb;
  const float* W_ih;
  const float* W_hh;
  const float* b_ih;
  const float* b_hh;
  const float* out_w;
  const float* out_b;
  const float* ehid;
  const int*   sos;
  float* h0;
  float* h1;
  float* ctx;
  unsigned long long* packed;
  float* logits_out;   // [B,T,V]
  float* attn_out;     // [B,T,S]
};

__global__ void __launch_bounds__(256) decode_kernel(DecArgs P) {
  cg::grid_group grid = cg::this_grid();
  const int bid = blockIdx.x;
  const int tid = threadIdx.x;

  // ---- shared (union of all phase needs; ~40 KB, 1+ block/CU is all we need) ----
  __shared__ __align__(16) float hb[Hn];
  __shared__ __align__(16) float qb[Hn];
  __shared__ __align__(16) float va[Hn];
  __shared__ float sp[64][4];
  __shared__ float wgt[64];
  __shared__ __align__(16) float ch[16][132];
  __shared__ int tks[16];
  __shared__ __align__(16) float hc[32][132];
  __shared__ float redm[32][33];
  __shared__ int   redi[32][33];

  // ---- init: h0 = ehid, packed = 0 (re-done every graph replay) ----
  for (int i = bid * 256 + tid; i < Bn * Hn; i += 250 * 256) P.h0[i] = P.ehid[i];
  for (int i = bid * 256 + tid; i < Tn * Bn; i += 250 * 256) P.packed[i] = 0ull;
  grid.sync();

  for (int t = 0; t < Tn; t++) {
    const float* h_cur = (t & 1) ? P.h1 : P.h0;
    float*       h_nxt = (t & 1) ? P.h0 : P.h1;

    // ================= phase 1: attention (blocks 0..31, one batch each) =============
    if (bid < Bn) {
      const int b = bid;
      for (int i = tid; i < Hn; i += 256) { hb[i] = h_cur[b * Hn + i]; va[i] = P.Va_w[i]; }
      __syncthreads();
      // q = Wa @ h + Wa_b
#pragma unroll
      for (int rr = 0; rr < 2; rr++) {
        const int r = tid + rr * 256;
        const float4* wrow = (const float4*)&P.Wa_w[r * Hn];
        float acc = 0.f;
        for (int k4 = 0; k4 < Hn / 4; k4++) {
          float4 w4 = wrow[k4];
          float4 h4 = *(const float4*)&hb[k4 * 4];
          acc += w4.x * h4.x + w4.y * h4.y + w4.z * h4.z + w4.w * h4.w;
        }
        qb[r] = acc + P.Wa_b[r];
      }
      __syncthreads();
      // scores[s] = sum_k tanh(q[k] + kp[b,s,k]) * Va[k]   (4 threads per s)
      {
        const int s = tid >> 2, j = tid & 3;
        const float* kprow = &P.kp[(b * Sn + s) * Hn];
        float acc = 0.f;
        for (int k = j * 128; k < j * 128 + 128; k++)
          acc += tanhf(qb[k] + kprow[k]) * va[k];
        sp[s][j] = acc;
      }
      __syncthreads();
      if (tid < 64) {
        float v = sp[tid][0] + sp[tid][1] + sp[tid][2] + sp[tid][3] + P.Va_b[0];
        float m = v;
        for (int off = 32; off; off >>= 1) m = fmaxf(m, __shfl_xor(m, off));
        float e = expf(v - m);
        float ssum = e;
        for (int off = 32; off; off >>= 1) ssum += __shfl_xor(ssum, off);
        float w = e / ssum;
        wgt[tid] = w;
        P.attn_out[(b * Tn + t) * Sn + tid] = w;
      }
      __syncthreads();
      // context = sum_s w[s] * enc[b,s,:]
#pragma unroll
      for (int rr = 0; rr < 2; rr++) {
        const int g = tid + rr * 256;
        float acc = 0.f;
        for (int s = 0; s < Sn; s++) acc += wgt[s] * P.enc[(b * Sn + s) * Hn + g];
        P.ctx[b * Hn + g] = acc;
      }
    }
    grid.sync();

    // ================= phase 2: GRU cell (blocks 0..63: 32 i-tiles x 2 b-tiles) ======
    if (bid < 64) {
      const int b_l = tid & 15, i_l = tid >> 4;  // 16 batches x 16 rows
      const int i0 = (bid & 31) * 16, b0 = (bid >> 5) * 16;
      const int ig = i0 + i_l;
      const int b  = b0 + b_l;
      if (tid < 16) {
        int tk;
        if (t == 0) {
          tk = P.sos[0];
        } else {
          unsigned long long pk = atomicAdd(&P.packed[(t - 1) * Bn + b0 + tid], 0ull);
          tk = (int)(0xFFFFFFFFu - (unsigned int)(pk & 0xFFFFFFFFull));
        }
        tks[tid] = tk;
      }
      __syncthreads();
      float air = 0, aiz = 0, ain = 0, ahr = 0, ahz = 0, ahn = 0;
      const float4* wr_r = (const float4*)&P.W_ih[(ig)        * 1024];
      const float4* wr_z = (const float4*)&P.W_ih[(ig + 512)  * 1024];
      const float4* wr_n = (const float4*)&P.W_ih[(ig + 1024) * 1024];
      // phase X: gi cols 0..511 (x = emb[tok])
      for (int c = 0; c < 4; c++) {
        const int k0 = c * 128;
#pragma unroll
        for (int r = 0; r < 8; r++) { int f = tid + r * 256; int bb = f >> 7, kk = f & 127;
          ch[bb][kk] = P.emb[tks[bb] * Hn + k0 + kk]; }
        __syncthreads();
#pragma unroll
        for (int k4 = 0; k4 < 32; k4++) {
          float4 x4 = *(const float4*)&ch[b_l][k4 * 4];
          float4 w;
          w = wr_r[(k0 >> 2) + k4]; air += w.x * x4.x + w.y * x4.y + w.z * x4.z + w.w * x4.w;
          w = wr_z[(k0 >> 2) + k4]; aiz += w.x * x4.x + w.y * x4.y + w.z * x4.z + w.w * x4.w;
          w = wr_n[(k0 >> 2) + k4]; ain += w.x * x4.x + w.y * x4.y + w.z * x4.z + w.w * x4.w;
        }
        __syncthreads();
      }
      // phase C: gi cols 512..1023 (context)
      for (int c = 0; c < 4; c++) {
        const int k0 = c * 128;
#pragma unroll
        for (int r = 0; r < 8; r++) { int f = tid + r * 256; int bb = f >> 7, kk = f & 127;
          ch[bb][kk] = P.ctx[(b0 + bb) * Hn + k0 + kk]; }
        __syncthreads();
#pragma unroll
        for (int k4 = 0; k4 < 32; k4++) {
          float4 x4 = *(const float4*)&ch[b_l][k4 * 4];
          float4 w;
          w = wr_r[128 + (k0 >> 2) + k4]; air += w.x * x4.x + w.y * x4.y + w.z * x4.z + w.w * x4.w;
          w = wr_z[128 + (k0 >> 2) + k4]; aiz += w.x * x4.x + w.y * x4.y + w.z * x4.z + w.w * x4.w;
          w = wr_n[128 + (k0 >> 2) + k4]; ain += w.x * x4.x + w.y * x4.y + w.z * x4.z + w.w * x4.w;
        }
        __syncthreads();
      }
      // phase H: gh (K = 512 over h)
      const float4* hr_r = (const float4*)&P.W_hh[(ig)        * Hn];
      const float4* hr_z = (const float4*)&P.W_hh[(ig + 512)  * Hn];
      const float4* hr_n = (const float4*)&P.W_hh[(ig + 1024) * Hn];
      for (int c = 0; c < 4; c++) {
        const int k0 = c * 128;
#pragma unroll
        for (int r = 0; r < 8; r++) { int f = tid + r * 256; int bb = f >> 7, kk = f & 127;
          ch[bb][kk] = h_cur[(b0 + bb) * Hn + k0 + kk]; }
        __syncthreads();
#pragma unroll
        for (int k4 = 0; k4 < 32; k4++) {
          float4 x4 = *(const float4*)&ch[b_l][k4 * 4];
          float4 w;
          w = hr_r[(k0 >> 2) + k4]; ahr += w.x * x4.x + w.y * x4.y + w.z * x4.z + w.w * x4.w;
          w = hr_z[(k0 >> 2) + k4]; ahz += w.x * x4.x + w.y * x4.y + w.z * x4.z + w.w * x4.w;
          w = hr_n[(k0 >> 2) + k4]; ahn += w.x * x4.x + w.y * x4.y + w.z * x4.z + w.w * x4.w;
        }
        __syncthreads();
      }
      const float hv = h_cur[b * Hn + ig];
      const float r = 1.f / (1.f + expf(-(air + P.b_ih[ig] + ahr + P.b_hh[ig])));
      const float z = 1.f / (1.f + expf(-(aiz + P.b_ih[512 + ig] + ahz + P.b_hh[512 + ig])));
      const float n = tanhf(ain + P.b_ih[1024 + ig] + r * (ahn + P.b_hh[1024 + ig]));
      h_nxt[b * Hn + ig] = (1.f - z) * n + z * hv;
    }
    grid.sync();

    // ================= phase 3: logits + packed argmax (all 250 blocks) ==============
    {
      const int vg = tid >> 3;   // 0..31
      const int bg = tid & 7;    // 0..7
      const int v0 = bid * 128;
      float acc[4][4];
#pragma unroll
      for (int j = 0; j < 4; j++)
#pragma unroll
        for (int i = 0; i < 4; i++) acc[j][i] = 0.f;
      const float* wbase = P.out_w + (v0 + vg * 4) * Hn;
      for (int kc = 0; kc < 4; kc++) {
        const int k0 = kc * 128;
#pragma unroll
        for (int r = 0; r < 16; r++) { int f = tid + r * 256; int bb = f >> 7, kk = f & 127;
          hc[bb][kk] = h_nxt[bb * Hn + k0 + kk]; }
        __syncthreads();
#pragma unroll
        for (int k4 = 0; k4 < 32; k4++) {
          float4 w4[4];
#pragma unroll
          for (int j = 0; j < 4; j++)
            w4[j] = *(const float4*)(wbase + j * Hn + k0 + k4 * 4);
#pragma unroll
          for (int i = 0; i < 4; i++) {
            float4 h4 = *(const float4*)&hc[bg + 8 * i][k4 * 4];
#pragma unroll
            for (int j = 0; j < 4; j++)
              acc[j][i] += w4[j].x * h4.x + w4[j].y * h4.y + w4[j].z * h4.z + w4[j].w * h4.w;
          }
        }
        __syncthreads();
      }
      float bias[4];
#pragma unroll
      for (int j = 0; j < 4; j++) bias[j] = P.out_b[v0 + vg * 4 + j];
#pragma unroll
      for (int i = 0; i < 4; i++) {
        const int b = bg + 8 * i;
        float best = -1e38f; int bidx = v0;
#pragma unroll
        for (int j = 0; j < 4; j++) {
          float x = acc[j][i] + bias[j];
          P.logits_out[(b * Tn + t) * Vn + v0 + vg * 4 + j] = x;
          if (x > best) { best = x; bidx = v0 + vg * 4 + j; }
        }
        redm[b][vg] = best; redi[b][vg] = bidx;
      }
      __syncthreads();
      if (tid < 32) {
        const int b = tid;
        float best = redm[b][0]; int bidx = redi[b][0];
        for (int g = 1; g < 32; g++)
          if (redm[b][g] > best) { best = redm[b][g]; bidx = redi[b][g]; }
        unsigned int u = __float_as_uint(best);
        unsigned int key = (u & 0x80000000u) ? ~u : (u | 0x80000000u);
        unsigned long long pk = ((unsigned long long)key << 32) |
                                (unsigned long long)(0xFFFFFFFFu - (unsigned int)bidx);
        atomicMax(&P.packed[t * Bn + b], pk);
      }
    }
    grid.sync();   // tok (packed[t]) + h_nxt now visible to everyone for step t+1
  }
}

// =====================================================================================
// Legacy per-step kernels — fallback only (used if cooperative launch is unavailable).
// =====================================================================================
__global__ void __launch_bounds__(256) init_kernel(const float* __restrict__ eh,
                                                   const int* __restrict__ sos,
                                                   float* __restrict__ h0,
                                                   unsigned long long* __restrict__ packed,
                                                   int* __restrict__ tok,
                                                   unsigned int* __restrict__ done) {
  const int tid = threadIdx.x;
  for (int i = tid; i < Bn * Hn; i += 256) h0[i] = eh[i];
  if (tid < Bn) tok[tid] = sos[0];
  for (int i = tid; i < Tn * Bn; i += 256) packed[i] = 0ull;
  if (tid < Tn) done[tid] = 0u;
}

__global__ void __launch_bounds__(256) attn_kernel(const float* __restrict__ enc,
                                                   const float* __restrict__ kp,
                                                   const float* __restrict__ Wa_w,
                                                   const float* __restrict__ Wa_b,
                                                   const float* __restrict__ Va_w,
                                                   const float* __restrict__ Va_b,
                                                   const float* __restrict__ h_cur,
                                                   float* __restrict__ ctx,
                                                   float* __restrict__ attn_out,
                                                   int t) {
  __shared__ __align__(16) float hb[Hn];
  __shared__ __align__(16) float qb[Hn];
  __shared__ __align__(16) float va[Hn];
  __shared__ float sp[64][4];
  __shared__ float wgt[64];
  const int b = blockIdx.x, tid = threadIdx.x;
  for (int i = tid; i < Hn; i += 256) { hb[i] = h_cur[b * Hn + i]; va[i] = Va_w[i]; }
  __syncthreads();
#pragma unroll
  for (int rr = 0; rr < 2; rr++) {
    const int r = tid + rr * 256;
    const float4* wrow = (const float4*)&Wa_w[r * Hn];
    float a = 0.f;
    for (int k4 = 0; k4 < Hn / 4; k4++) {
      float4 w4 = wrow[k4];
      float4 h4 = *(const float4*)&hb[k4 * 4];
      a += w4.x * h4.x + w4.y * h4.y + w4.z * h4.z + w4.w * h4.w;
    }
    qb[r] = a + Wa_b[r];
  }
  __syncthreads();
  {
    const int s = tid >> 2, j = tid & 3;
    const float* kprow = &kp[(b * Sn + s) * Hn];
    float a = 0.f;
    for (int k = j * 128; k < j * 128 + 128; k++)
      a += tanhf(qb[k] + kprow[k]) * va[k];
    sp[s][j] = a;
  }
  __syncthreads();
  if (tid < 64) {
    float v = sp[tid][0] + sp[tid][1] + sp[tid][2] + sp[tid][3] + Va_b[0];
    float m = v;
    for (int off = 32; off; off >>= 1) m = fmaxf(m, __shfl_xor(m, off));
    float e = expf(v - m);
    float ssum = e;
    for (int off = 32; off; off >>= 1) ssum += __shfl_xor(ssum, off);
    float w = e / ssum;
    wgt[tid] = w;
    attn_out[(b * Tn + t) * Sn + tid] = w;
  }
  __syncthreads();
#pragma unroll
  for (int rr = 0; rr < 2; rr++) {
    const int g = tid + rr * 256;
    float a = 0.f;
    for (int s = 0; s < Sn; s++) a += wgt[s] * enc[(b * Sn + s) * Hn + g];
    ctx[b * Hn + g] = a;
  }
}

__global__ void __launch_bounds__(256) gru_kernel(const float* __restrict__ emb,
                                                  const int* __restrict__ tok,
                                                  const float* __restrict__ ctx,
                                                  const float* __restrict__ h_cur,
                                                  const float* __restrict__ W_ih,
                                                  const float* __restrict__ W_hh,
                                                  const float* __restrict__ b_ih,
                                                  const float* __restrict__ b_hh,
                                                  float* __restrict__ h_nxt) {
  __shared__ __align__(16) float ch[16][132];
  __shared__ int tks[16];
  const int tid = threadIdx.x;
  const int b_l = tid & 15, i_l = tid >> 4;
  const int i0 = blockIdx.x * 16, b0 = blockIdx.y * 16;
  const int ig = i0 + i_l;
  const int b  = b0 + b_l;
  if (tid < 16) tks[tid] = tok[b0 + tid];
  __syncthreads();
  float air = 0, aiz = 0, ain = 0, ahr = 0, ahz = 0, ahn = 0;
  const float4* wr_r = (const float4*)&W_ih[(ig)          * 1024];
  const float4* wr_z = (const float4*)&W_ih[(ig + 512)    * 1024];
  const float4* wr_n = (const float4*)&W_ih[(ig + 1024)   * 1024];
  for (int c = 0; c < 4; c++) {
    const int k0 = c * 128;
#pragma unroll
    for (int r = 0; r < 8; r++) { int f = tid + r * 256; int bb = f >> 7, kk = f & 127;
      ch[bb][kk] = emb[tks[bb] * Hn + k0 + kk]; }
    __syncthreads();
#pragma unroll
    for (int k4 = 0; k4 < 32; k4++) {
      float4 x4 = *(const float4*)&ch[b_l][k4 * 4];
      float4 w;
      w = wr_r[(k0 >> 2) + k4]; air += w.x * x4.x + w.y * x4.y + w.z * x4.z + w.w * x4.w;
      w = wr_z[(k0 >> 2) + k4]; aiz += w.x * x4.x + w.y * x4.y + w.z * x4.z + w.w * x4.w;
      w = wr_n[(k0 >> 2) + k4]; ain += w.x * x4.x + w.y * x4.y + w.z * x4.z + w.w * x4.w;
    }
    __syncthreads();
  }
  for (int c = 0; c < 4; c++) {
    const int k0 = c * 128;
#pragma unroll
    for (int r = 0; r < 8; r++) { int f = tid + r * 256; int bb = f >> 7, kk = f & 127;
      ch[bb][kk] = ctx[(b0 + bb) * Hn + k0 + kk]; }
    __syncthreads();
#pragma unroll
    for (int k4 = 0; k4 < 32; k4++) {
      float4 x4 = *(const float4*)&ch[b_l][k4 * 4];
      float4 w;
      w = wr_r[128 + (k0 >> 2) + k4]; air += w.x * x4.x + w.y * x4.y + w.z * x4.z + w.w * x4.w;
      w = wr_z[128 + (k0 >> 2) + k4]; aiz += w.x * x4.x + w.y * x4.y + w.z * x4.z + w.w * x4.w;
      w = wr_n[128 + (k0 >> 2) + k4]; ain += w.x * x4.x + w.y * x4.y + w.z * x4.z + w.w * x4.w;
    }
    __syncthreads();
  }
  const float4* hr_r = (const float4*)&W_hh[(ig)        * Hn];
  const float4* hr_z = (const float4*)&W_hh[(ig + 512)  * Hn];
  const float4* hr_n = (const float4*)&W_hh[(ig + 1024) * Hn];
  for (int c = 0; c < 4; c++) {
    const int k0 = c * 128;
#pragma unroll
    for (int r = 0; r < 8; r++) { int f = tid + r * 256; int bb = f >> 7, kk = f & 127;
      ch[bb][kk] = h_cur[(b0 + bb) * Hn + k0 + kk]; }
    __syncthreads();
#pragma unroll
    for (int k4 = 0; k4 < 32; k4++) {
      float4 x4 = *(const float4*)&ch[b_l][k4 * 4];
      float4 w;
      w = hr_r[(k0 >> 2) + k4]; ahr += w.x * x4.x + w.y * x4.y + w.z * x4.z + w.w * x4.w;
      w = hr_z[(k0 >> 2) + k4]; ahz += w.x * x4.x + w.y * x4.y + w.z * x4.z + w.w * x4.w;
      w = hr_n[(k0 >> 2) + k4]; ahn += w.x * x4.x + w.y * x4.y + w.z * x4.z + w.w * x4.w;
    }
    __syncthreads();
  }
  const float hv = h_cur[b * Hn + ig];
  const float r = 1.f / (1.f + expf(-(air + b_ih[ig] + ahr + b_hh[ig])));
  const float z = 1.f / (1.f + expf(-(aiz + b_ih[512 + ig] + ahz + b_hh[512 + ig])));
  const float n = tanhf(ain + b_ih[1024 + ig] + r * (ahn + b_hh[1024 + ig]));
  h_nxt[b * Hn + ig] = (1.f - z) * n + z * hv;
}

__global__ void __launch_bounds__(256) logits_kernel(const float* __restrict__ h_new,
                                                     const float* __restrict__ out_w,
                                                     const float* __restrict__ out_b,
                                                     float* __restrict__ logits_out,
                                                     unsigned long long* __restrict__ packed,
                                                     int* __restrict__ tok,
                                                     unsigned int* __restrict__ done,
                                                     int t) {
  __shared__ __align__(16) float hc[32][132];
  __shared__ float redm[32][33];
  __shared__ int   redi[32][33];
  __shared__ unsigned int rank;
  const int tid = threadIdx.x;
  const int vg = tid >> 3;
  const int bg = tid & 7;
  const int v0 = blockIdx.x * 128;
  float acc[4][4];
#pragma unroll
  for (int j = 0; j < 4; j++)
#pragma unroll
    for (int i = 0; i < 4; i++) acc[j][i] = 0.f;
  const float* wbase = out_w + (v0 + vg * 4) * Hn;
  for (int kc = 0; kc < 4; kc++) {
    const int k0 = kc * 128;
#pragma unroll
    for (int r = 0; r < 16; r++) { int f = tid + r * 256; int bb = f >> 7, kk = f & 127;
      hc[bb][kk] = h_new[bb * Hn + k0 + kk]; }
    __syncthreads();
#pragma unroll
    for (int k4 = 0; k4 < 32; k4++) {
      float4 w4[4];
#pragma unroll
      for (int j = 0; j < 4; j++)
        w4[j] = *(const float4*)(wbase + j * Hn + k0 + k4 * 4);
#pragma unroll
      for (int i = 0; i < 4; i++) {
        float4 h4 = *(const float4*)&hc[bg + 8 * i][k4 * 4];
#pragma unroll
        for (int j = 0; j < 4; j++)
          acc[j][i] += w4[j].x * h4.x + w4[j].y * h4.y + w4[j].z * h4.z + w4[j].w * h4.w;
      }
    }
    __syncthreads();
  }
  float bias[4];
#pragma unroll
  for (int j = 0; j < 4; j++) bias[j] = out_b[v0 + vg * 4 + j];
#pragma unroll
  for (int i = 0; i < 4; i++) {
    const int b = bg + 8 * i;
    float best = -1e38f; int bidx = v0;
#pragma unroll
    for (int j = 0; j < 4; j++) {
      float x = acc[j][i] + bias[j];
      logits_out[(b * Tn + t) * Vn + v0 + vg * 4 + j] = x;
      if (x > best) { best = x; bidx = v0 + vg * 4 + j; }
    }
    redm[b][vg] = best; redi[b][vg] = bidx;
  }
  __syncthreads();
  if (tid < 32) {
    const int b = tid;
    float best = redm[b][0]; int bidx = redi[b][0];
    for (int g = 1; g < 32; g++)
      if (redm[b][g] > best) { best = redm[b][g]; bidx = redi[b][g]; }
    unsigned int u = __float_as_uint(best);
    unsigned int key = (u & 0x80000000u) ? ~u : (u | 0x80000000u);
    unsigned long long pk = ((unsigned long long)key << 32) |
                            (unsigned long long)(0xFFFFFFFFu - (unsigned int)bidx);
    atomicMax(&packed[t * Bn + b], pk);
  }
  __threadfence();
  if (tid == 0) rank = atomicAdd(&done[t], 1u);
  __syncthreads();
  if (rank == gridDim.x - 1) {
    __threadfence();
    if (tid < 32) {
      unsigned long long pk = atomicAdd(&packed[t * Bn + tid], 0ull);
      tok[tid] = (int)(0xFFFFFFFFu - (unsigned int)(pk & 0xFFFFFFFFull));
    }
  }
}

// ---------------- finalize: in-place log_softmax over each (b,t) row + h_last copy ----------------
__global__ void __launch_bounds__(256) finalize_kernel(float* __restrict__ out1,
                                                       const float* __restrict__ h_src,
                                                       float* __restrict__ out2) {
  if (blockIdx.x == (unsigned)(Bn * Tn)) {
    for (int i = threadIdx.x; i < Bn * Hn; i += 256) out2[i] = h_src[i];
    return;
  }
  float* row = out1 + (size_t)blockIdx.x * Vn;
  const int tid = threadIdx.x;
  __shared__ float red[4];
  const float4* r4 = (const float4*)row;
  float m = -1e38f;
  for (int i = tid; i < Vn / 4; i += 256) {
    float4 v = r4[i];
    m = fmaxf(m, fmaxf(fmaxf(v.x, v.y), fmaxf(v.z, v.w)));
  }
  for (int off = 32; off; off >>= 1) m = fmaxf(m, __shfl_xor(m, off));
  if ((tid & 63) == 0) red[tid >> 6] = m;
  __syncthreads();
  m = fmaxf(fmaxf(red[0], red[1]), fmaxf(red[2], red[3]));
  __syncthreads();
  float s = 0.f;
  for (int i = tid; i < Vn / 4; i += 256) {
    float4 v = r4[i];
    s += __expf(v.x - m) + __expf(v.y - m) + __expf(v.z - m) + __expf(v.w - m);
  }
  for (int off = 32; off; off >>= 1) s += __shfl_xor(s, off);
  if ((tid & 63) == 0) red[tid >> 6] = s;
  __syncthreads();
  s = red[0] + red[1] + red[2] + red[3];
  const float lz = m + logf(s);
  float4* w4p = (float4*)row;
  for (int i = tid; i < Vn / 4; i += 256) {
    float4 v = r4[i];
    v.x -= lz; v.y -= lz; v.z -= lz; v.w -= lz;
    w4p[i] = v;
  }
}

extern "C" void kernel_launch(void* const* d_in, const int* in_sizes, int n_in,
                              void* d_out, int out_size, void* d_ws, size_t ws_size,
                              hipStream_t stream) {
  (void)in_sizes; (void)n_in; (void)out_size; (void)ws_size;
  const float* enc   = (const float*)d_in[0];
  const float* ehid  = (const float*)d_in[1];
  const float* emb   = (const float*)d_in[2];
  const float* Wa_w  = (const float*)d_in[3];
  const float* Wa_b  = (const float*)d_in[4];
  const float* Ua_w  = (const float*)d_in[5];
  const float* Ua_b  = (const float*)d_in[6];
  const float* Va_w  = (const float*)d_in[7];
  const float* Va_b  = (const float*)d_in[8];
  const float* W_ih  = (const float*)d_in[9];
  const float* W_hh  = (const float*)d_in[10];
  const float* b_ih  = (const float*)d_in[11];
  const float* b_hh  = (const float*)d_in[12];
  const float* out_w = (const float*)d_in[13];
  const float* out_b = (const float*)d_in[14];
  const int*   sos   = (const int*)d_in[15];

  float* ws    = (float*)d_ws;
  float* kp    = ws + KP_OFF;
  float* hbuf0 = ws + H0_OFF;
  float* hbuf1 = ws + H1_OFF;
  float* ctx   = ws + CTX_OFF;
  unsigned long long* packed = (unsigned long long*)(ws + PK_OFF);
  int*          tok  = (int*)(ws + TOK_OFF);
  unsigned int* done = (unsigned int*)(ws + DONE_OFF);

  float* out1 = (float*)d_out;                    // logprobs [B,T,V]
  float* out2 = out1 + (size_t)Bn * Tn * Vn;      // h_last [1,B,H]
  float* out3 = out2 + Bn * Hn;                   // attn [B,T,S]

  kp_kernel<<<dim3(64, 8), 256, 0, stream>>>(enc, Ua_w, Ua_b, kp);

  DecArgs P;
  P.enc = enc; P.kp = kp; P.Wa_w = Wa_w; P.Wa_b = Wa_b; P.Va_w = Va_w; P.Va_b = Va_b;
  P.emb = emb; P.W_ih = W_ih; P.W_hh = W_hh; P.b_ih = b_ih; P.b_hh = b_hh;
  P.out_w = out_w; P.out_b = out_b; P.ehid = ehid; P.sos = sos;
  P.h0 = hbuf0; P.h1 = hbuf1; P.ctx = ctx; P.packed = packed;
  P.logits_out = out1; P.attn_out = out3;
  void* kargs[] = { (void*)&P };
  hipError_t err = hipLaunchCooperativeKernel(decode_kernel, dim3(250), dim3(256),
                                              kargs, 0u, stream);
  if (err != hipSuccess) {
    // Fallback: legacy per-step kernel sequence (identical math).
    (void)hipGetLastError();
    init_kernel<<<1, 256, 0, stream>>>(ehid, sos, hbuf0, packed, tok, done);
    for (int t = 0; t < Tn; t++) {
      float* h_cur = (t & 1) ? hbuf1 : hbuf0;
      float* h_nxt = (t & 1) ? hbuf0 : hbuf1;
      attn_kernel<<<Bn, 256, 0, stream>>>(enc, kp, Wa_w, Wa_b, Va_w, Va_b, h_cur, ctx, out3, t);
      gru_kernel<<<dim3(32, 2), 256, 0, stream>>>(emb, tok, ctx, h_cur, W_ih, W_hh, b_ih, b_hh, h_nxt);
      logits_kernel<<<250, 256, 0, stream>>>(h_nxt, out_w, out_b, out1, packed, tok, done, t);
    }
  }
  finalize_kernel<<<Bn * Tn + 1, 256, 0, stream>>>(out1, hbuf0, out2);
}

// Round 2
// 13651.692 us; speedup vs baseline: 1.4728x; 1.4728x over previous
//
#include <hip/hip_runtime.h>

#define Bn 32
#define Sn 64
#define Tn 64
#define Hn 512
#define Vn 32000

// ---- workspace layout (float offsets) ----
#define KP_OFF   0u            // keys_proj: 2048*512 = 1048576
#define H0_OFF   1048576u      // h buffer 0: 16384
#define H1_OFF   1064960u      // h buffer 1: 16384
#define CTX_OFF  1081344u      // context: 16384
#define PK_OFF   1097728u      // packed argmax: 64*32 ull = 4096 float slots (8B aligned)
#define TOK_OFF  1101824u      // tok: 32 int
#define DONE_OFF 1101856u      // done counters: 64 uint

// ---------------- keys_proj = einsum('bsh,gh->bsg', enc, Ua_w) + Ua_b ----------------
__global__ void __launch_bounds__(256) kp_kernel(const float* __restrict__ enc,
                                                 const float* __restrict__ Ua_w,
                                                 const float* __restrict__ Ua_b,
                                                 float* __restrict__ kp) {
  __shared__ __align__(16) float ea[32][68];
  __shared__ __align__(16) float ua[64][68];
  const int tid = threadIdx.x;
  const int bs0 = blockIdx.x * 32, g0 = blockIdx.y * 64;
  const int g_l = tid & 63;   // 0..63
  const int wv  = tid >> 6;   // 0..3
  float acc[8];
#pragma unroll
  for (int r = 0; r < 8; r++) acc[r] = 0.f;
  for (int kc = 0; kc < 8; kc++) {
    const int k0 = kc * 64;
#pragma unroll
    for (int r = 0; r < 8; r++) { int f = tid + r * 256; int b = f >> 6, k = f & 63;
      ea[b][k] = enc[(bs0 + b) * Hn + k0 + k]; }
#pragma unroll
    for (int r = 0; r < 16; r++) { int f = tid + r * 256; int g = f >> 6, k = f & 63;
      ua[g][k] = Ua_w[(g0 + g) * Hn + k0 + k]; }
    __syncthreads();
#pragma unroll
    for (int kk = 0; kk < 16; kk++) {
      float4 u4 = *(const float4*)&ua[g_l][kk * 4];
#pragma unroll
      for (int r = 0; r < 8; r++) {
        int bs_l = wv + 4 * r;
        float4 e4 = *(const float4*)&ea[bs_l][kk * 4];
        acc[r] += u4.x * e4.x + u4.y * e4.y + u4.z * e4.z + u4.w * e4.w;
      }
    }
    __syncthreads();
  }
  const float bias = Ua_b[g0 + g_l];
#pragma unroll
  for (int r = 0; r < 8; r++) {
    int bs = bs0 + wv + 4 * r;
    kp[bs * Hn + g0 + g_l] = acc[r] + bias;
  }
}

// ---------------- init: h0, tok, packed, done ----------------
__global__ void __launch_bounds__(256) init_kernel(const float* __restrict__ eh,
                                                   const int* __restrict__ sos,
                                                   float* __restrict__ h0,
                                                   unsigned long long* __restrict__ packed,
                                                   int* __restrict__ tok,
                                                   unsigned int* __restrict__ done) {
  const int tid = threadIdx.x;
  for (int i = tid; i < Bn * Hn; i += 256) h0[i] = eh[i];
  if (tid < Bn) tok[tid] = sos[0];
  for (int i = tid; i < Tn * Bn; i += 256) packed[i] = 0ull;
  if (tid < Tn) done[tid] = 0u;
}

// ---------------- attention: q, scores, softmax (-> attn out), context ----------------
__global__ void __launch_bounds__(256) attn_kernel(const float* __restrict__ enc,
                                                   const float* __restrict__ kp,
                                                   const float* __restrict__ Wa_w,
                                                   const float* __restrict__ Wa_b,
                                                   const float* __restrict__ Va_w,
                                                   const float* __restrict__ Va_b,
                                                   const float* __restrict__ h_cur,
                                                   float* __restrict__ ctx,
                                                   float* __restrict__ attn_out,
                                                   int t) {
  __shared__ __align__(16) float hb[Hn];
  __shared__ __align__(16) float qb[Hn];
  __shared__ __align__(16) float va[Hn];
  __shared__ float sp[64][4];
  __shared__ float wgt[64];
  const int b = blockIdx.x, tid = threadIdx.x;
  for (int i = tid; i < Hn; i += 256) { hb[i] = h_cur[b * Hn + i]; va[i] = Va_w[i]; }
  __syncthreads();
  // q = Wa @ h + Wa_b
#pragma unroll
  for (int rr = 0; rr < 2; rr++) {
    const int r = tid + rr * 256;
    const float4* wrow = (const float4*)&Wa_w[r * Hn];
    float a = 0.f;
    for (int k4 = 0; k4 < Hn / 4; k4++) {
      float4 w4 = wrow[k4];
      float4 h4 = *(const float4*)&hb[k4 * 4];
      a += w4.x * h4.x + w4.y * h4.y + w4.z * h4.z + w4.w * h4.w;
    }
    qb[r] = a + Wa_b[r];
  }
  __syncthreads();
  // scores[s] = sum_k tanh(q[k] + kp[b,s,k]) * Va[k]   (4 threads per s)
  // float4 loads; separate += statements preserve the scalar accumulation order.
  {
    const int s = tid >> 2, j = tid & 3;
    const float4* kp4 = (const float4*)&kp[(b * Sn + s) * Hn + j * 128];
    const float4* q4p = (const float4*)&qb[j * 128];
    const float4* v4p = (const float4*)&va[j * 128];
    float a = 0.f;
#pragma unroll 8
    for (int k4 = 0; k4 < 32; k4++) {
      float4 kv = kp4[k4];
      float4 q4 = q4p[k4];
      float4 v4 = v4p[k4];
      a += tanhf(q4.x + kv.x) * v4.x;
      a += tanhf(q4.y + kv.y) * v4.y;
      a += tanhf(q4.z + kv.z) * v4.z;
      a += tanhf(q4.w + kv.w) * v4.w;
    }
    sp[s][j] = a;
  }
  __syncthreads();
  if (tid < 64) {
    float v = sp[tid][0] + sp[tid][1] + sp[tid][2] + sp[tid][3] + Va_b[0];
    float m = v;
    for (int off = 32; off; off >>= 1) m = fmaxf(m, __shfl_xor(m, off));
    float e = expf(v - m);
    float ssum = e;
    for (int off = 32; off; off >>= 1) ssum += __shfl_xor(ssum, off);
    float w = e / ssum;
    wgt[tid] = w;
    attn_out[(b * Tn + t) * Sn + tid] = w;
  }
  __syncthreads();
  // context = sum_s w[s] * enc[b,s,:]
#pragma unroll
  for (int rr = 0; rr < 2; rr++) {
    const int g = tid + rr * 256;
    float a = 0.f;
    for (int s = 0; s < Sn; s++) a += wgt[s] * enc[(b * Sn + s) * Hn + g];
    ctx[b * Hn + g] = a;
  }
}

// ---------------- GRU cell: h_nxt from (emb[tok], ctx, h_cur) ----------------
__global__ void __launch_bounds__(256) gru_kernel(const float* __restrict__ emb,
                                                  const int* __restrict__ tok,
                                                  const float* __restrict__ ctx,
                                                  const float* __restrict__ h_cur,
                                                  const float* __restrict__ W_ih,
                                                  const float* __restrict__ W_hh,
                                                  const float* __restrict__ b_ih,
                                                  const float* __restrict__ b_hh,
                                                  float* __restrict__ h_nxt) {
  __shared__ __align__(16) float ch[16][132];
  __shared__ int tks[16];
  const int tid = threadIdx.x;
  const int b_l = tid & 15, i_l = tid >> 4;  // 16 batches x 16 rows
  const int i0 = blockIdx.x * 16, b0 = blockIdx.y * 16;
  const int ig = i0 + i_l;
  const int b  = b0 + b_l;
  if (tid < 16) tks[tid] = tok[b0 + tid];
  __syncthreads();
  float air = 0, aiz = 0, ain = 0, ahr = 0, ahz = 0, ahn = 0;
  const float4* wr_r = (const float4*)&W_ih[(ig)          * 1024];
  const float4* wr_z = (const float4*)&W_ih[(ig + 512)    * 1024];
  const float4* wr_n = (const float4*)&W_ih[(ig + 1024)   * 1024];
  // phase X: gi cols 0..511 (x = emb[tok])
  for (int c = 0; c < 4; c++) {
    const int k0 = c * 128;
#pragma unroll
    for (int r = 0; r < 8; r++) { int f = tid + r * 256; int bb = f >> 7, kk = f & 127;
      ch[bb][kk] = emb[tks[bb] * Hn + k0 + kk]; }
    __syncthreads();
#pragma unroll
    for (int k4 = 0; k4 < 32; k4++) {
      float4 x4 = *(const float4*)&ch[b_l][k4 * 4];
      float4 w;
      w = wr_r[(k0 >> 2) + k4]; air += w.x * x4.x + w.y * x4.y + w.z * x4.z + w.w * x4.w;
      w = wr_z[(k0 >> 2) + k4]; aiz += w.x * x4.x + w.y * x4.y + w.z * x4.z + w.w * x4.w;
      w = wr_n[(k0 >> 2) + k4]; ain += w.x * x4.x + w.y * x4.y + w.z * x4.z + w.w * x4.w;
    }
    __syncthreads();
  }
  // phase C: gi cols 512..1023 (context)
  for (int c = 0; c < 4; c++) {
    const int k0 = c * 128;
#pragma unroll
    for (int r = 0; r < 8; r++) { int f = tid + r * 256; int bb = f >> 7, kk = f & 127;
      ch[bb][kk] = ctx[(b0 + bb) * Hn + k0 + kk]; }
    __syncthreads();
#pragma unroll
    for (int k4 = 0; k4 < 32; k4++) {
      float4 x4 = *(const float4*)&ch[b_l][k4 * 4];
      float4 w;
      w = wr_r[128 + (k0 >> 2) + k4]; air += w.x * x4.x + w.y * x4.y + w.z * x4.z + w.w * x4.w;
      w = wr_z[128 + (k0 >> 2) + k4]; aiz += w.x * x4.x + w.y * x4.y + w.z * x4.z + w.w * x4.w;
      w = wr_n[128 + (k0 >> 2) + k4]; ain += w.x * x4.x + w.y * x4.y + w.z * x4.z + w.w * x4.w;
    }
    __syncthreads();
  }
  // phase H: gh (K = 512 over h)
  const float4* hr_r = (const float4*)&W_hh[(ig)        * Hn];
  const float4* hr_z = (const float4*)&W_hh[(ig + 512)  * Hn];
  const float4* hr_n = (const float4*)&W_hh[(ig + 1024) * Hn];
  for (int c = 0; c < 4; c++) {
    const int k0 = c * 128;
#pragma unroll
    for (int r = 0; r < 8; r++) { int f = tid + r * 256; int bb = f >> 7, kk = f & 127;
      ch[bb][kk] = h_cur[(b0 + bb) * Hn + k0 + kk]; }
    __syncthreads();
#pragma unroll
    for (int k4 = 0; k4 < 32; k4++) {
      float4 x4 = *(const float4*)&ch[b_l][k4 * 4];
      float4 w;
      w = hr_r[(k0 >> 2) + k4]; ahr += w.x * x4.x + w.y * x4.y + w.z * x4.z + w.w * x4.w;
      w = hr_z[(k0 >> 2) + k4]; ahz += w.x * x4.x + w.y * x4.y + w.z * x4.z + w.w * x4.w;
      w = hr_n[(k0 >> 2) + k4]; ahn += w.x * x4.x + w.y * x4.y + w.z * x4.z + w.w * x4.w;
    }
    __syncthreads();
  }
  const float hv = h_cur[b * Hn + ig];
  const float r = 1.f / (1.f + expf(-(air + b_ih[ig] + ahr + b_hh[ig])));
  const float z = 1.f / (1.f + expf(-(aiz + b_ih[512 + ig] + ahz + b_hh[512 + ig])));
  const float n = tanhf(ain + b_ih[1024 + ig] + r * (ahn + b_hh[1024 + ig]));
  h_nxt[b * Hn + ig] = (1.f - z) * n + z * hv;
}

// ---------------- logits + argmax(token feedback) ----------------
// v2: 500 blocks x (64 vocab rows x 32 batches). Full h staged in LDS once (no kc
// phases -> one straight K=512 run of independent float4 weight loads).
// Thread: vg = tid>>3 owns 2 rows (vg*2+j), bg = tid&7 owns 4 batches (b = bg+8i).
// FP accumulation order per output identical to v1 (ascending k, 4-product groups).
__global__ void __launch_bounds__(256) logits_kernel(const float* __restrict__ h_new,
                                                     const float* __restrict__ out_w,
                                                     const float* __restrict__ out_b,
                                                     float* __restrict__ logits_out,
                                                     unsigned long long* __restrict__ packed,
                                                     int* __restrict__ tok,
                                                     unsigned int* __restrict__ done,
                                                     int t) {
  __shared__ __align__(16) float hc[32][516];   // 66 KB, padded: 8 rows span all 32 banks
  __shared__ float redm[32][33];
  __shared__ int   redi[32][33];
  __shared__ unsigned int rank;
  const int tid = threadIdx.x;
  const int vg = tid >> 3;   // 0..31 -> rows vg*2, vg*2+1
  const int bg = tid & 7;    // 0..7  -> batches bg+8i
  const int v0 = blockIdx.x * 64;
  // stage all of h: 32 x 512 floats, float4 copies
  for (int f = tid; f < Bn * (Hn / 4); f += 256) {
    int bb = f >> 7, kk = f & 127;
    *(float4*)&hc[bb][kk * 4] = *(const float4*)&h_new[bb * Hn + kk * 4];
  }
  __syncthreads();
  float acc[2][4];
#pragma unroll
  for (int j = 0; j < 2; j++)
#pragma unroll
    for (int i = 0; i < 4; i++) acc[j][i] = 0.f;
  const float* wbase = out_w + (size_t)(v0 + vg * 2) * Hn;
#pragma unroll 8
  for (int k4 = 0; k4 < 128; k4++) {
    float4 w0 = *(const float4*)(wbase + 0 * Hn + k4 * 4);
    float4 w1 = *(const float4*)(wbase + 1 * Hn + k4 * 4);
#pragma unroll
    for (int i = 0; i < 4; i++) {
      float4 h4 = *(const float4*)&hc[bg + 8 * i][k4 * 4];
      acc[0][i] += w0.x * h4.x + w0.y * h4.y + w0.z * h4.z + w0.w * h4.w;
      acc[1][i] += w1.x * h4.x + w1.y * h4.y + w1.z * h4.z + w1.w * h4.w;
    }
  }
  float bias[2];
#pragma unroll
  for (int j = 0; j < 2; j++) bias[j] = out_b[v0 + vg * 2 + j];
#pragma unroll
  for (int i = 0; i < 4; i++) {
    const int b = bg + 8 * i;
    float best = -1e38f; int bidx = v0;
#pragma unroll
    for (int j = 0; j < 2; j++) {
      float x = acc[j][i] + bias[j];
      logits_out[((size_t)b * Tn + t) * Vn + v0 + vg * 2 + j] = x;
      if (x > best) { best = x; bidx = v0 + vg * 2 + j; }
    }
    redm[b][vg] = best; redi[b][vg] = bidx;
  }
  __syncthreads();
  if (tid < 32) {
    const int b = tid;
    float best = redm[b][0]; int bidx = redi[b][0];
    for (int g = 1; g < 32; g++)
      if (redm[b][g] > best) { best = redm[b][g]; bidx = redi[b][g]; }
    unsigned int u = __float_as_uint(best);
    unsigned int key = (u & 0x80000000u) ? ~u : (u | 0x80000000u);
    unsigned long long pk = ((unsigned long long)key << 32) |
                            (unsigned long long)(0xFFFFFFFFu - (unsigned int)bidx);
    atomicMax(&packed[t * Bn + b], pk);
  }
  __threadfence();
  if (tid == 0) rank = atomicAdd(&done[t], 1u);
  __syncthreads();
  if (rank == gridDim.x - 1) {
    __threadfence();
    if (tid < 32) {
      unsigned long long pk = atomicAdd(&packed[t * Bn + tid], 0ull);
      tok[tid] = (int)(0xFFFFFFFFu - (unsigned int)(pk & 0xFFFFFFFFull));
    }
  }
}

// ---------------- finalize: in-place log_softmax over each (b,t) row + h_last copy ----------------
__global__ void __launch_bounds__(256) finalize_kernel(float* __restrict__ out1,
                                                       const float* __restrict__ h_src,
                                                       float* __restrict__ out2) {
  if (blockIdx.x == (unsigned)(Bn * Tn)) {
    for (int i = threadIdx.x; i < Bn * Hn; i += 256) out2[i] = h_src[i];
    return;
  }
  float* row = out1 + (size_t)blockIdx.x * Vn;
  const int tid = threadIdx.x;
  __shared__ float red[4];
  const float4* r4 = (const float4*)row;
  float m = -1e38f;
  for (int i = tid; i < Vn / 4; i += 256) {
    float4 v = r4[i];
    m = fmaxf(m, fmaxf(fmaxf(v.x, v.y), fmaxf(v.z, v.w)));
  }
  for (int off = 32; off; off >>= 1) m = fmaxf(m, __shfl_xor(m, off));
  if ((tid & 63) == 0) red[tid >> 6] = m;
  __syncthreads();
  m = fmaxf(fmaxf(red[0], red[1]), fmaxf(red[2], red[3]));
  __syncthreads();
  float s = 0.f;
  for (int i = tid; i < Vn / 4; i += 256) {
    float4 v = r4[i];
    s += __expf(v.x - m) + __expf(v.y - m) + __expf(v.z - m) + __expf(v.w - m);
  }
  for (int off = 32; off; off >>= 1) s += __shfl_xor(s, off);
  if ((tid & 63) == 0) red[tid >> 6] = s;
  __syncthreads();
  s = red[0] + red[1] + red[2] + red[3];
  const float lz = m + logf(s);
  float4* w4p = (float4*)row;
  for (int i = tid; i < Vn / 4; i += 256) {
    float4 v = r4[i];
    v.x -= lz; v.y -= lz; v.z -= lz; v.w -= lz;
    w4p[i] = v;
  }
}

extern "C" void kernel_launch(void* const* d_in, const int* in_sizes, int n_in,
                              void* d_out, int out_size, void* d_ws, size_t ws_size,
                              hipStream_t stream) {
  (void)in_sizes; (void)n_in; (void)out_size; (void)ws_size;
  const float* enc   = (const float*)d_in[0];
  const float* ehid  = (const float*)d_in[1];
  const float* emb   = (const float*)d_in[2];
  const float* Wa_w  = (const float*)d_in[3];
  const float* Wa_b  = (const float*)d_in[4];
  const float* Ua_w  = (const float*)d_in[5];
  const float* Ua_b  = (const float*)d_in[6];
  const float* Va_w  = (const float*)d_in[7];
  const float* Va_b  = (const float*)d_in[8];
  const float* W_ih  = (const float*)d_in[9];
  const float* W_hh  = (const float*)d_in[10];
  const float* b_ih  = (const float*)d_in[11];
  const float* b_hh  = (const float*)d_in[12];
  const float* out_w = (const float*)d_in[13];
  const float* out_b = (const float*)d_in[14];
  const int*   sos   = (const int*)d_in[15];

  float* ws    = (float*)d_ws;
  float* kp    = ws + KP_OFF;
  float* hbuf0 = ws + H0_OFF;
  float* hbuf1 = ws + H1_OFF;
  float* ctx   = ws + CTX_OFF;
  unsigned long long* packed = (unsigned long long*)(ws + PK_OFF);
  int*          tok  = (int*)(ws + TOK_OFF);
  unsigned int* done = (unsigned int*)(ws + DONE_OFF);

  float* out1 = (float*)d_out;                    // logprobs [B,T,V]
  float* out2 = out1 + (size_t)Bn * Tn * Vn;      // h_last [1,B,H]
  float* out3 = out2 + Bn * Hn;                   // attn [B,T,S]

  kp_kernel<<<dim3(64, 8), 256, 0, stream>>>(enc, Ua_w, Ua_b, kp);
  init_kernel<<<1, 256, 0, stream>>>(ehid, sos, hbuf0, packed, tok, done);
  for (int t = 0; t < Tn; t++) {
    float* h_cur = (t & 1) ? hbuf1 : hbuf0;
    float* h_nxt = (t & 1) ? hbuf0 : hbuf1;
    attn_kernel<<<Bn, 256, 0, stream>>>(enc, kp, Wa_w, Wa_b, Va_w, Va_b, h_cur, ctx, out3, t);
    gru_kernel<<<dim3(32, 2), 256, 0, stream>>>(emb, tok, ctx, h_cur, W_ih, W_hh, b_ih, b_hh, h_nxt);
    logits_kernel<<<500, 256, 0, stream>>>(h_nxt, out_w, out_b, out1, packed, tok, done, t);
  }
  finalize_kernel<<<Bn * Tn + 1, 256, 0, stream>>>(out1, hbuf0, out2);
}

// Round 3
// 11011.326 us; speedup vs baseline: 1.8259x; 1.2398x over previous
//
#include <hip/hip_runtime.h>

#define Bn 32
#define Sn 64
#define Tn 64
#define Hn 512
#define Vn 32000

// ---- workspace layout (float offsets) ----
#define KP_OFF   0u            // keys_proj: 2048*512 = 1048576
#define H0_OFF   1048576u      // h buffer 0: 16384
#define H1_OFF   1064960u      // h buffer 1: 16384
#define CTX_OFF  1081344u      // context: 16384
#define PK_OFF   1097728u      // packed argmax: 64*32 ull = 4096 float slots (8B aligned)
#define CTL_OFF  1101824u      // ctl: 64 uint (ticket bits0-15 | flagA bits16-23 | flagB bits24-31)
// end 1101888 floats (within the original ~4.4 MB footprint)

// ---------------- agent-scope (device, L2-bypassing) atomic helpers ----------------
__device__ __forceinline__ float agl(const float* p) {
  return __hip_atomic_load(p, __ATOMIC_RELAXED, __HIP_MEMORY_SCOPE_AGENT);
}
__device__ __forceinline__ void ags(float* p, float v) {
  __hip_atomic_store(p, v, __ATOMIC_RELAXED, __HIP_MEMORY_SCOPE_AGENT);
}

// ---------------- keys_proj = einsum('bsh,gh->bsg', enc, Ua_w) + Ua_b ----------------
__global__ void __launch_bounds__(256) kp_kernel(const float* __restrict__ enc,
                                                 const float* __restrict__ Ua_w,
                                                 const float* __restrict__ Ua_b,
                                                 float* __restrict__ kp) {
  __shared__ __align__(16) float ea[32][68];
  __shared__ __align__(16) float ua[64][68];
  const int tid = threadIdx.x;
  const int bs0 = blockIdx.x * 32, g0 = blockIdx.y * 64;
  const int g_l = tid & 63;   // 0..63
  const int wv  = tid >> 6;   // 0..3
  float acc[8];
#pragma unroll
  for (int r = 0; r < 8; r++) acc[r] = 0.f;
  for (int kc = 0; kc < 8; kc++) {
    const int k0 = kc * 64;
#pragma unroll
    for (int r = 0; r < 8; r++) { int f = tid + r * 256; int b = f >> 6, k = f & 63;
      ea[b][k] = enc[(bs0 + b) * Hn + k0 + k]; }
#pragma unroll
    for (int r = 0; r < 16; r++) { int f = tid + r * 256; int g = f >> 6, k = f & 63;
      ua[g][k] = Ua_w[(g0 + g) * Hn + k0 + k]; }
    __syncthreads();
#pragma unroll
    for (int kk = 0; kk < 16; kk++) {
      float4 u4 = *(const float4*)&ua[g_l][kk * 4];
#pragma unroll
      for (int r = 0; r < 8; r++) {
        int bs_l = wv + 4 * r;
        float4 e4 = *(const float4*)&ea[bs_l][kk * 4];
        acc[r] += u4.x * e4.x + u4.y * e4.y + u4.z * e4.z + u4.w * e4.w;
      }
    }
    __syncthreads();
  }
  const float bias = Ua_b[g0 + g_l];
#pragma unroll
  for (int r = 0; r < 8; r++) {
    int bs = bs0 + wv + 4 * r;
    kp[bs * Hn + g0 + g_l] = acc[r] + bias;
  }
}

// ---------------- init: h0, packed, ctl ----------------
__global__ void __launch_bounds__(256) init_kernel(const float* __restrict__ eh,
                                                   float* __restrict__ h0,
                                                   unsigned long long* __restrict__ packed,
                                                   unsigned int* __restrict__ ctl) {
  const int tid = threadIdx.x;
  for (int i = tid; i < Bn * Hn; i += 256) h0[i] = eh[i];
  for (int i = tid; i < Tn * Bn; i += 256) packed[i] = 0ull;
  if (tid < Tn) ctl[tid] = 0u;
}

// =====================================================================================
// Fused per-step kernel: 596 blocks. Arrival-order tickets assign roles:
//   tickets 0..31   -> attention (one batch each)
//   tickets 32..95  -> GRU tiles (32 i-tiles x 2 b-tiles)
//   tickets 96..595 -> logits slices (64 vocab rows each)
// Handoffs (ctx: attn->gru, h_nxt: gru->logits) go through agent-scope atomics
// (coherence-point access, no stale-L2 hazard). Deadlock-free: workers are the
// first-arriving (hence resident) blocks; waiters only wait on earlier arrivals.
// Phase math identical to the harness-verified per-step kernels.
// =====================================================================================
__global__ void __launch_bounds__(256, 2) step_kernel(
    const float* __restrict__ enc, const float* __restrict__ kp,
    const float* __restrict__ Wa_w, const float* __restrict__ Wa_b,
    const float* __restrict__ Va_w, const float* __restrict__ Va_b,
    const float* __restrict__ emb, const float* __restrict__ W_ih,
    const float* __restrict__ W_hh, const float* __restrict__ b_ih,
    const float* __restrict__ b_hh, const float* __restrict__ out_w,
    const float* __restrict__ out_b, const int* __restrict__ sos,
    const float* __restrict__ h_cur, float* __restrict__ h_nxt,
    float* __restrict__ ctx, unsigned long long* __restrict__ packed,
    unsigned int* __restrict__ ctl,
    float* __restrict__ logits_out, float* __restrict__ attn_out, int t) {
  // union'd LDS: max(attn 7.4KB, gru 8.5KB, logits 74.5KB)
  __shared__ __align__(16) char smem[74496];
  __shared__ unsigned int s_tk;
  const int tid = threadIdx.x;
  if (tid == 0)
    s_tk = __hip_atomic_fetch_add(&ctl[t], 1u, __ATOMIC_RELAXED,
                                  __HIP_MEMORY_SCOPE_AGENT) & 0xFFFFu;
  __syncthreads();
  const unsigned int tk = s_tk;

  if (tk < 32u) {
    // ================= attention for batch b =================
    const int b = (int)tk;
    float* hb  = (float*)smem;       // [512]
    float* qb  = hb + Hn;            // [512]
    float* va  = qb + Hn;            // [512]
    float* sp  = va + Hn;            // [64][4]
    float* wgt = sp + 256;           // [64]
    for (int i = tid; i < Hn; i += 256) { hb[i] = h_cur[b * Hn + i]; va[i] = Va_w[i]; }
    __syncthreads();
    // q = Wa @ h + Wa_b
#pragma unroll
    for (int rr = 0; rr < 2; rr++) {
      const int r = tid + rr * 256;
      const float4* wrow = (const float4*)&Wa_w[r * Hn];
      float a = 0.f;
      for (int k4 = 0; k4 < Hn / 4; k4++) {
        float4 w4 = wrow[k4];
        float4 h4 = *(const float4*)&hb[k4 * 4];
        a += w4.x * h4.x + w4.y * h4.y + w4.z * h4.z + w4.w * h4.w;
      }
      qb[r] = a + Wa_b[r];
    }
    __syncthreads();
    // scores[s] = sum_k tanh(q[k] + kp[b,s,k]) * Va[k]   (4 threads per s)
    {
      const int s = tid >> 2, j = tid & 3;
      const float4* kp4 = (const float4*)&kp[(b * Sn + s) * Hn + j * 128];
      const float4* q4p = (const float4*)&qb[j * 128];
      const float4* v4p = (const float4*)&va[j * 128];
      float a = 0.f;
#pragma unroll 8
      for (int k4 = 0; k4 < 32; k4++) {
        float4 kv = kp4[k4];
        float4 q4 = q4p[k4];
        float4 v4 = v4p[k4];
        a += tanhf(q4.x + kv.x) * v4.x;
        a += tanhf(q4.y + kv.y) * v4.y;
        a += tanhf(q4.z + kv.z) * v4.z;
        a += tanhf(q4.w + kv.w) * v4.w;
      }
      sp[s * 4 + j] = a;
    }
    __syncthreads();
    if (tid < 64) {
      float v = sp[tid * 4 + 0] + sp[tid * 4 + 1] + sp[tid * 4 + 2] + sp[tid * 4 + 3] + Va_b[0];
      float m = v;
      for (int off = 32; off; off >>= 1) m = fmaxf(m, __shfl_xor(m, off));
      float e = expf(v - m);
      float ssum = e;
      for (int off = 32; off; off >>= 1) ssum += __shfl_xor(ssum, off);
      float w = e / ssum;
      wgt[tid] = w;
      attn_out[(b * Tn + t) * Sn + tid] = w;
    }
    __syncthreads();
    // context = sum_s w[s] * enc[b,s,:]  (agent-scope store: handoff to gru)
#pragma unroll
    for (int rr = 0; rr < 2; rr++) {
      const int g = tid + rr * 256;
      float a = 0.f;
      for (int s = 0; s < Sn; s++) a += wgt[s] * enc[(b * Sn + s) * Hn + g];
      ags(&ctx[b * Hn + g], a);
    }
    __syncthreads();   // drains vmem (stores complete at coherence point)
    if (tid == 0)
      __hip_atomic_fetch_add(&ctl[t], 1u << 16, __ATOMIC_RELEASE, __HIP_MEMORY_SCOPE_AGENT);

  } else if (tk < 96u) {
    // ================= GRU tile =================
    const int g = (int)tk - 32;
    const int b_l = tid & 15, i_l = tid >> 4;  // 16 batches x 16 rows
    const int i0 = (g & 31) * 16, b0 = (g >> 5) * 16;
    const int ig = i0 + i_l;
    const int b  = b0 + b_l;
    float* ch = (float*)smem;                  // [16][132]
    int* tks  = (int*)(ch + 16 * 132);
    if (tid < 16) {
      int tkn;
      if (t == 0) {
        tkn = sos[0];
      } else {
        unsigned long long pk = __hip_atomic_load(&packed[(t - 1) * Bn + b0 + tid],
                                                  __ATOMIC_RELAXED, __HIP_MEMORY_SCOPE_AGENT);
        tkn = (int)(0xFFFFFFFFu - (unsigned int)(pk & 0xFFFFFFFFull));
      }
      tks[tid] = tkn;
    }
    __syncthreads();
    float air = 0, aiz = 0, ain = 0, ahr = 0, ahz = 0, ahn = 0;
    const float4* wr_r = (const float4*)&W_ih[(size_t)(ig)        * 1024];
    const float4* wr_z = (const float4*)&W_ih[(size_t)(ig + 512)  * 1024];
    const float4* wr_n = (const float4*)&W_ih[(size_t)(ig + 1024) * 1024];
    // phase X: gi cols 0..511 (x = emb[tok]) — independent of ctx
    for (int c = 0; c < 4; c++) {
      const int k0 = c * 128;
#pragma unroll
      for (int r = 0; r < 8; r++) { int f = tid + r * 256; int bb = f >> 7, kk = f & 127;
        ch[bb * 132 + kk] = emb[(size_t)tks[bb] * Hn + k0 + kk]; }
      __syncthreads();
#pragma unroll
      for (int k4 = 0; k4 < 32; k4++) {
        float4 x4 = *(const float4*)&ch[b_l * 132 + k4 * 4];
        float4 w;
        w = wr_r[(k0 >> 2) + k4]; air += w.x * x4.x + w.y * x4.y + w.z * x4.z + w.w * x4.w;
        w = wr_z[(k0 >> 2) + k4]; aiz += w.x * x4.x + w.y * x4.y + w.z * x4.z + w.w * x4.w;
        w = wr_n[(k0 >> 2) + k4]; ain += w.x * x4.x + w.y * x4.y + w.z * x4.z + w.w * x4.w;
      }
      __syncthreads();
    }
    // phase H: gh (K = 512 over h) — independent of ctx, overlaps attn
    const float4* hr_r = (const float4*)&W_hh[(size_t)(ig)        * Hn];
    const float4* hr_z = (const float4*)&W_hh[(size_t)(ig + 512)  * Hn];
    const float4* hr_n = (const float4*)&W_hh[(size_t)(ig + 1024) * Hn];
    for (int c = 0; c < 4; c++) {
      const int k0 = c * 128;
#pragma unroll
      for (int r = 0; r < 8; r++) { int f = tid + r * 256; int bb = f >> 7, kk = f & 127;
        ch[bb * 132 + kk] = h_cur[(b0 + bb) * Hn + k0 + kk]; }
      __syncthreads();
#pragma unroll
      for (int k4 = 0; k4 < 32; k4++) {
        float4 x4 = *(const float4*)&ch[b_l * 132 + k4 * 4];
        float4 w;
        w = hr_r[(k0 >> 2) + k4]; ahr += w.x * x4.x + w.y * x4.y + w.z * x4.z + w.w * x4.w;
        w = hr_z[(k0 >> 2) + k4]; ahz += w.x * x4.x + w.y * x4.y + w.z * x4.z + w.w * x4.w;
        w = hr_n[(k0 >> 2) + k4]; ahn += w.x * x4.x + w.y * x4.y + w.z * x4.z + w.w * x4.w;
      }
      __syncthreads();
    }
    // wait for attention (flagA == 32)
    if (tid == 0) {
      while (((__hip_atomic_load(&ctl[t], __ATOMIC_RELAXED, __HIP_MEMORY_SCOPE_AGENT) >> 16) & 0xFFu) < 32u)
        __builtin_amdgcn_s_sleep(8);
    }
    __syncthreads();
    asm volatile("" ::: "memory");
    // phase C: gi cols 512..1023 (context) — agent-scope loads
    for (int c = 0; c < 4; c++) {
      const int k0 = c * 128;
#pragma unroll
      for (int r = 0; r < 8; r++) { int f = tid + r * 256; int bb = f >> 7, kk = f & 127;
        ch[bb * 132 + kk] = agl(&ctx[(b0 + bb) * Hn + k0 + kk]); }
      __syncthreads();
#pragma unroll
      for (int k4 = 0; k4 < 32; k4++) {
        float4 x4 = *(const float4*)&ch[b_l * 132 + k4 * 4];
        float4 w;
        w = wr_r[128 + (k0 >> 2) + k4]; air += w.x * x4.x + w.y * x4.y + w.z * x4.z + w.w * x4.w;
        w = wr_z[128 + (k0 >> 2) + k4]; aiz += w.x * x4.x + w.y * x4.y + w.z * x4.z + w.w * x4.w;
        w = wr_n[128 + (k0 >> 2) + k4]; ain += w.x * x4.x + w.y * x4.y + w.z * x4.z + w.w * x4.w;
      }
      __syncthreads();
    }
    const float hv = h_cur[b * Hn + ig];
    const float r = 1.f / (1.f + expf(-(air + b_ih[ig] + ahr + b_hh[ig])));
    const float z = 1.f / (1.f + expf(-(aiz + b_ih[512 + ig] + ahz + b_hh[512 + ig])));
    const float n = tanhf(ain + b_ih[1024 + ig] + r * (ahn + b_hh[1024 + ig]));
    ags(&h_nxt[b * Hn + ig], (1.f - z) * n + z * hv);
    __syncthreads();   // drains vmem
    if (tid == 0)
      __hip_atomic_fetch_add(&ctl[t], 1u << 24, __ATOMIC_RELEASE, __HIP_MEMORY_SCOPE_AGENT);

  } else {
    // ================= logits slice (64 vocab rows) =================
    const int v0 = ((int)tk - 96) * 64;
    float* hc   = (float*)smem;          // [32][516]
    float* redm = hc + 32 * 516;         // [32][33]
    int*   redi = (int*)(redm + 32 * 33);
    const int vg = tid >> 3;   // 0..31 -> rows vg*2, vg*2+1
    const int bg = tid & 7;    // 0..7  -> batches bg+8i
    // prewarm out_w slice into L2 while waiting (skip if h already ready)
    bool ready = ((__hip_atomic_load(&ctl[t], __ATOMIC_RELAXED, __HIP_MEMORY_SCOPE_AGENT) >> 24) >= 64u);
    if (!ready) {
      const float4* wb4 = (const float4*)(out_w + (size_t)v0 * Hn);
      float d = 0.f;
      for (int f = tid; f < 64 * 128; f += 256) {
        float4 v = wb4[f];
        d += v.x + v.y + v.z + v.w;
      }
      asm volatile("" :: "v"(d));
    }
    // wait for GRU (flagB == 64)
    if (tid == 0) {
      while ((__hip_atomic_load(&ctl[t], __ATOMIC_RELAXED, __HIP_MEMORY_SCOPE_AGENT) >> 24) < 64u)
        __builtin_amdgcn_s_sleep(8);
    }
    __syncthreads();
    asm volatile("" ::: "memory");
    // stage h (agent-scope loads: handoff from gru)
    for (int f = tid; f < Bn * Hn; f += 256) {
      int bb = f >> 9, kk = f & 511;
      hc[bb * 516 + kk] = agl(&h_nxt[f]);
    }
    __syncthreads();
    float acc[2][4];
#pragma unroll
    for (int j = 0; j < 2; j++)
#pragma unroll
      for (int i = 0; i < 4; i++) acc[j][i] = 0.f;
    const float* wbase = out_w + (size_t)(v0 + vg * 2) * Hn;
#pragma unroll 8
    for (int k4 = 0; k4 < 128; k4++) {
      float4 w0 = *(const float4*)(wbase + 0 * Hn + k4 * 4);
      float4 w1 = *(const float4*)(wbase + 1 * Hn + k4 * 4);
#pragma unroll
      for (int i = 0; i < 4; i++) {
        float4 h4 = *(const float4*)&hc[(bg + 8 * i) * 516 + k4 * 4];
        acc[0][i] += w0.x * h4.x + w0.y * h4.y + w0.z * h4.z + w0.w * h4.w;
        acc[1][i] += w1.x * h4.x + w1.y * h4.y + w1.z * h4.z + w1.w * h4.w;
      }
    }
    float bias[2];
#pragma unroll
    for (int j = 0; j < 2; j++) bias[j] = out_b[v0 + vg * 2 + j];
#pragma unroll
    for (int i = 0; i < 4; i++) {
      const int b = bg + 8 * i;
      float best = -1e38f; int bidx = v0;
#pragma unroll
      for (int j = 0; j < 2; j++) {
        float x = acc[j][i] + bias[j];
        __builtin_nontemporal_store(x, &logits_out[((size_t)b * Tn + t) * Vn + v0 + vg * 2 + j]);
        if (x > best) { best = x; bidx = v0 + vg * 2 + j; }
      }
      redm[b * 33 + vg] = best; redi[b * 33 + vg] = bidx;
    }
    __syncthreads();
    if (tid < 32) {
      const int b = tid;
      float best = redm[b * 33 + 0]; int bidx = redi[b * 33 + 0];
      for (int g2 = 1; g2 < 32; g2++)
        if (redm[b * 33 + g2] > best) { best = redm[b * 33 + g2]; bidx = redi[b * 33 + g2]; }
      unsigned int u = __float_as_uint(best);
      unsigned int key = (u & 0x80000000u) ? ~u : (u | 0x80000000u);
      unsigned long long pk = ((unsigned long long)key << 32) |
                              (unsigned long long)(0xFFFFFFFFu - (unsigned int)bidx);
      atomicMax(&packed[t * Bn + b], pk);
    }
  }
}

// ---------------- finalize: in-place log_softmax over each (b,t) row + h_last copy ----------------
__global__ void __launch_bounds__(256) finalize_kernel(float* __restrict__ out1,
                                                       const float* __restrict__ h_src,
                                                       float* __restrict__ out2) {
  if (blockIdx.x == (unsigned)(Bn * Tn)) {
    for (int i = threadIdx.x; i < Bn * Hn; i += 256) out2[i] = h_src[i];
    return;
  }
  float* row = out1 + (size_t)blockIdx.x * Vn;
  const int tid = threadIdx.x;
  __shared__ float red[4];
  const float4* r4 = (const float4*)row;
  float m = -1e38f;
  for (int i = tid; i < Vn / 4; i += 256) {
    float4 v = r4[i];
    m = fmaxf(m, fmaxf(fmaxf(v.x, v.y), fmaxf(v.z, v.w)));
  }
  for (int off = 32; off; off >>= 1) m = fmaxf(m, __shfl_xor(m, off));
  if ((tid & 63) == 0) red[tid >> 6] = m;
  __syncthreads();
  m = fmaxf(fmaxf(red[0], red[1]), fmaxf(red[2], red[3]));
  __syncthreads();
  float s = 0.f;
  for (int i = tid; i < Vn / 4; i += 256) {
    float4 v = r4[i];
    s += __expf(v.x - m) + __expf(v.y - m) + __expf(v.z - m) + __expf(v.w - m);
  }
  for (int off = 32; off; off >>= 1) s += __shfl_xor(s, off);
  if ((tid & 63) == 0) red[tid >> 6] = s;
  __syncthreads();
  s = red[0] + red[1] + red[2] + red[3];
  const float lz = m + logf(s);
  float4* w4p = (float4*)row;
  for (int i = tid; i < Vn / 4; i += 256) {
    float4 v = r4[i];
    v.x -= lz; v.y -= lz; v.z -= lz; v.w -= lz;
    w4p[i] = v;
  }
}

extern "C" void kernel_launch(void* const* d_in, const int* in_sizes, int n_in,
                              void* d_out, int out_size, void* d_ws, size_t ws_size,
                              hipStream_t stream) {
  (void)in_sizes; (void)n_in; (void)out_size; (void)ws_size;
  const float* enc   = (const float*)d_in[0];
  const float* ehid  = (const float*)d_in[1];
  const float* emb   = (const float*)d_in[2];
  const float* Wa_w  = (const float*)d_in[3];
  const float* Wa_b  = (const float*)d_in[4];
  const float* Ua_w  = (const float*)d_in[5];
  const float* Ua_b  = (const float*)d_in[6];
  const float* Va_w  = (const float*)d_in[7];
  const float* Va_b  = (const float*)d_in[8];
  const float* W_ih  = (const float*)d_in[9];
  const float* W_hh  = (const float*)d_in[10];
  const float* b_ih  = (const float*)d_in[11];
  const float* b_hh  = (const float*)d_in[12];
  const float* out_w = (const float*)d_in[13];
  const float* out_b = (const float*)d_in[14];
  const int*   sos   = (const int*)d_in[15];

  float* ws    = (float*)d_ws;
  float* kp    = ws + KP_OFF;
  float* hbuf0 = ws + H0_OFF;
  float* hbuf1 = ws + H1_OFF;
  float* ctx   = ws + CTX_OFF;
  unsigned long long* packed = (unsigned long long*)(ws + PK_OFF);
  unsigned int* ctl = (unsigned int*)(ws + CTL_OFF);

  float* out1 = (float*)d_out;                    // logprobs [B,T,V]
  float* out2 = out1 + (size_t)Bn * Tn * Vn;      // h_last [1,B,H]
  float* out3 = out2 + Bn * Hn;                   // attn [B,T,S]

  kp_kernel<<<dim3(64, 8), 256, 0, stream>>>(enc, Ua_w, Ua_b, kp);
  init_kernel<<<1, 256, 0, stream>>>(ehid, hbuf0, packed, ctl);
  for (int t = 0; t < Tn; t++) {
    float* h_cur = (t & 1) ? hbuf1 : hbuf0;
    float* h_nxt = (t & 1) ? hbuf0 : hbuf1;
    step_kernel<<<596, 256, 0, stream>>>(enc, kp, Wa_w, Wa_b, Va_w, Va_b,
                                         emb, W_ih, W_hh, b_ih, b_hh,
                                         out_w, out_b, sos,
                                         h_cur, h_nxt, ctx, packed, ctl,
                                         out1, out3, t);
  }
  finalize_kernel<<<Bn * Tn + 1, 256, 0, stream>>>(out1, hbuf0, out2);
}